// Round 1
// baseline (796.714 us; speedup 1.0000x reference)
//
#include <hip/hip_runtime.h>
#include <math.h>

#define D 128

// ---------------------------------------------------------------------------
// Kernel 1: w_vec[d] = sum_k W_edge[k] * W1[D+k][d]
//           c_vec[d] = sum_k b_edge[k] * W1[D+k][d] + b1[d]
// ---------------------------------------------------------------------------
__global__ __launch_bounds__(128) void prep_wc_kernel(
    const float* __restrict__ W_edge, const float* __restrict__ b_edge,
    const float* __restrict__ W1, const float* __restrict__ b1,
    float* __restrict__ wc)
{
    int d = threadIdx.x;
    float w = 0.f, c = 0.f;
    for (int k = 0; k < D; ++k) {
        float w1 = W1[(size_t)(D + k) * D + d];
        w = fmaf(W_edge[k], w1, w);
        c = fmaf(b_edge[k], w1, c);
    }
    wc[d]     = w;
    wc[D + d] = c + b1[d];
}

// ---------------------------------------------------------------------------
// Kernel 2: detect whether edge_index arrived as int64 or int32.
// If int64 (little-endian), the high 32-bit word of every element is 0
// (indices are < N << 2^31). If int32, odd positions are random indices;
// the chance that 1024 of them are all zero is ~(1/N)^1024 ~ 0.
// flag = 1 -> treat as int64, flag = 0 -> int32.
// ---------------------------------------------------------------------------
__global__ __launch_bounds__(256) void detect_kernel(
    const int* __restrict__ idx32, int n_check, int* __restrict__ flag)
{
    __shared__ int nz;
    if (threadIdx.x == 0) nz = 0;
    __syncthreads();
    int local = 0;
    for (int i = threadIdx.x; i < n_check; i += blockDim.x)
        if (idx32[2 * i + 1] != 0) local = 1;
    if (local) atomicOr(&nz, 1);
    __syncthreads();
    if (threadIdx.x == 0) *flag = (nz == 0) ? 1 : 0;
}

// ---------------------------------------------------------------------------
// Kernel 3: node GEMM, out[n][d] = sum_k A[n][k] * W[k][d]  (+ x + deg*b2)
// W (128x128 fp32, 64 KB) staged in LDS. 256 threads = 2 rows/iteration,
// thread owns one output channel d. LDS read pattern: 64 lanes hit 32 banks
// 2-way at distinct addresses -> free (m136). A[k] loads are wave-uniform
// broadcasts served by L1/L2.
// ---------------------------------------------------------------------------
__global__ __launch_bounds__(256) void node_gemm_kernel(
    const float* __restrict__ A, const float* __restrict__ W,
    const float* __restrict__ addx, const float* __restrict__ deg,
    const float* __restrict__ bvec, float* __restrict__ out, int N)
{
    __shared__ float w[D * D];
    for (int i = threadIdx.x; i < D * D; i += 256) w[i] = W[i];
    __syncthreads();

    const int d   = threadIdx.x & (D - 1);
    const int sub = threadIdx.x >> 7;           // 0 or 1
    const float bv = bvec ? bvec[d] : 0.f;

    for (int n = blockIdx.x * 2 + sub; n < N; n += gridDim.x * 2) {
        const float4* a4 = (const float4*)(A + (size_t)n * D);
        float acc = 0.f;
        #pragma unroll 8
        for (int k4 = 0; k4 < D / 4; ++k4) {
            float4 av = a4[k4];                 // wave-uniform broadcast load
            int kb = k4 * 4;
            acc = fmaf(av.x, w[(kb + 0) * D + d], acc);
            acc = fmaf(av.y, w[(kb + 1) * D + d], acc);
            acc = fmaf(av.z, w[(kb + 2) * D + d], acc);
            acc = fmaf(av.w, w[(kb + 3) * D + d], acc);
        }
        if (addx) acc += addx[(size_t)n * D + d];
        if (deg)  acc = fmaf(deg[n], bv, acc);
        out[(size_t)n * D + d] = acc;
    }
}

// ---------------------------------------------------------------------------
// Kernel 4: per-edge. One wave per edge; lane owns channels 2*lane, 2*lane+1.
// h = relu(y[col] + dist*w_vec + c_vec); atomicAdd into H[row]; count deg.
// ---------------------------------------------------------------------------
__global__ __launch_bounds__(256) void edge_kernel(
    const float* __restrict__ coord, const float* __restrict__ y,
    const float* __restrict__ wc, const void* __restrict__ eidx,
    const int* __restrict__ flag, float* __restrict__ H,
    float* __restrict__ deg, int E)
{
    const int lane  = threadIdx.x & 63;
    const int wib   = threadIdx.x >> 6;
    const int wpb   = blockDim.x >> 6;
    const int wave  = blockIdx.x * wpb + wib;
    const int nwave = gridDim.x * wpb;

    const bool is64 = (*flag != 0);
    const long long* e64 = (const long long*)eidx;
    const int*       e32 = (const int*)eidx;

    const float2 wv = ((const float2*)wc)[lane];         // w_vec[2l..2l+1]
    const float2 cv = ((const float2*)(wc + D))[lane];   // c_vec[2l..2l+1]

    for (int e = wave; e < E; e += nwave) {
        int row, col;
        if (is64) { row = (int)e64[e]; col = (int)e64[E + e]; }
        else      { row = e32[e];      col = e32[E + e];      }

        float dx = coord[row * 3 + 0] - coord[col * 3 + 0];
        float dy = coord[row * 3 + 1] - coord[col * 3 + 1];
        float dz = coord[row * 3 + 2] - coord[col * 3 + 2];
        float dist = sqrtf(fmaf(dx, dx, fmaf(dy, dy, dz * dz)));

        float2 yv = *(const float2*)(y + (size_t)col * D + lane * 2);
        float h0 = fmaxf(0.f, fmaf(dist, wv.x, yv.x + cv.x));
        float h1 = fmaxf(0.f, fmaf(dist, wv.y, yv.y + cv.y));

        float* hp = H + (size_t)row * D + lane * 2;
        atomicAdd(hp,     h0);
        atomicAdd(hp + 1, h1);
        if (lane == 0) atomicAdd(deg + row, 1.0f);
    }
}

// ---------------------------------------------------------------------------
extern "C" void kernel_launch(void* const* d_in, const int* in_sizes, int n_in,
                              void* d_out, int out_size, void* d_ws, size_t ws_size,
                              hipStream_t stream)
{
    const float* x      = (const float*)d_in[0];
    const float* coord  = (const float*)d_in[1];
    const void*  eidx   = d_in[2];
    const float* W_edge = (const float*)d_in[3];
    const float* b_edge = (const float*)d_in[4];
    const float* W1     = (const float*)d_in[5];
    const float* b1     = (const float*)d_in[6];
    const float* W2     = (const float*)d_in[7];
    const float* b2     = (const float*)d_in[8];

    const int N = in_sizes[1] / 3;       // coord is [N,3]
    const int E = in_sizes[2] / 2;       // edge_index is [2,E]

    // Workspace layout (floats): H [N*D] | deg [N] | wc [2*D] | flag
    float* ws   = (float*)d_ws;
    float* H    = ws;
    float* deg  = H + (size_t)N * D;
    float* wc   = deg + N;
    int*   flag = (int*)(wc + 2 * D);

    // y = x @ W1_top lives in d_out (fully overwritten by the final GEMM).
    float* y = (float*)d_out;

    // Zero H and deg (contiguous) — must happen every call (atomics).
    hipMemsetAsync(H, 0, ((size_t)N * D + N) * sizeof(float), stream);

    prep_wc_kernel<<<1, 128, 0, stream>>>(W_edge, b_edge, W1, b1, wc);
    detect_kernel<<<1, 256, 0, stream>>>((const int*)eidx,
                                         (E < 1024 ? E : 1024), flag);
    node_gemm_kernel<<<1024, 256, 0, stream>>>(x, W1, nullptr, nullptr,
                                               nullptr, y, N);
    edge_kernel<<<2048, 256, 0, stream>>>(coord, y, wc, eidx, flag, H, deg, E);
    node_gemm_kernel<<<1024, 256, 0, stream>>>(H, W2, x, deg, b2,
                                               (float*)d_out, N);
}

// Round 2
// 424.896 us; speedup vs baseline: 1.8751x; 1.8751x over previous
//
#include <hip/hip_runtime.h>
#include <hip/hip_fp16.h>
#include <hip/hip_bf16.h>
#include <math.h>

#define D 128

typedef unsigned int  u32;
typedef unsigned short u16;

// ---------------------------------------------------------------------------
// Kernel 1: w_vec[d] = sum_k W_edge[k] * W1[D+k][d]
//           c_vec[d] = sum_k b_edge[k] * W1[D+k][d] + b1[d]
// ---------------------------------------------------------------------------
__global__ __launch_bounds__(128) void prep_wc_kernel(
    const float* __restrict__ W_edge, const float* __restrict__ b_edge,
    const float* __restrict__ W1, const float* __restrict__ b1,
    float* __restrict__ wc)
{
    int d = threadIdx.x;
    float w = 0.f, c = 0.f;
    for (int k = 0; k < D; ++k) {
        float w1 = W1[(size_t)(D + k) * D + d];
        w = fmaf(W_edge[k], w1, w);
        c = fmaf(b_edge[k], w1, c);
    }
    wc[d]     = w;
    wc[D + d] = c + b1[d];
}

// ---------------------------------------------------------------------------
// Kernel 2: int64-vs-int32 edge_index detection (high words all 0 => int64).
// ---------------------------------------------------------------------------
__global__ __launch_bounds__(256) void detect_kernel(
    const int* __restrict__ idx32, int n_check, int* __restrict__ flag)
{
    __shared__ int nz;
    if (threadIdx.x == 0) nz = 0;
    __syncthreads();
    int local = 0;
    for (int i = threadIdx.x; i < n_check; i += blockDim.x)
        if (idx32[2 * i + 1] != 0) local = 1;
    if (local) atomicOr(&nz, 1);
    __syncthreads();
    if (threadIdx.x == 0) *flag = (nz == 0) ? 1 : 0;
}

// ---------------------------------------------------------------------------
// Kernel 3: per-row edge counts (int atomics, cheap).
// ---------------------------------------------------------------------------
__global__ __launch_bounds__(256) void count_kernel(
    const void* __restrict__ eidx, const int* __restrict__ flag,
    u32* __restrict__ counts, int E)
{
    const bool is64 = (*flag != 0);
    const long long* e64 = (const long long*)eidx;
    const int*       e32 = (const int*)eidx;
    for (int e = blockIdx.x * blockDim.x + threadIdx.x; e < E;
         e += gridDim.x * blockDim.x) {
        int row = is64 ? (int)e64[e] : e32[e];
        atomicAdd(&counts[row], 1u);
    }
}

// ---------------------------------------------------------------------------
// Kernels 4a/4b/4c: exclusive scan of counts -> offsets (N <= 65536 assumed:
// number of 256-chunks <= 256, so one block scans the chunk sums).
// ---------------------------------------------------------------------------
__global__ __launch_bounds__(256) void scanA_kernel(
    const u32* __restrict__ counts, u32* __restrict__ chunkSum, int N)
{
    __shared__ u32 s[256];
    int t = threadIdx.x, i = blockIdx.x * 256 + t;
    s[t] = (i < N) ? counts[i] : 0u;
    __syncthreads();
    for (int off = 128; off > 0; off >>= 1) {
        if (t < off) s[t] += s[t + off];
        __syncthreads();
    }
    if (t == 0) chunkSum[blockIdx.x] = s[0];
}

__global__ __launch_bounds__(256) void scanB_kernel(
    const u32* __restrict__ chunkSum, u32* __restrict__ chunkBase,
    u32* __restrict__ offsets, int NCH, int N)
{
    __shared__ u32 s[256];
    int t = threadIdx.x;
    u32 v = (t < NCH) ? chunkSum[t] : 0u;
    s[t] = v;
    __syncthreads();
    for (int off = 1; off < 256; off <<= 1) {
        u32 a = (t >= off) ? s[t - off] : 0u;
        __syncthreads();
        s[t] += a;
        __syncthreads();
    }
    if (t < NCH) chunkBase[t] = s[t] - v;     // exclusive
    if (t == 255) offsets[N] = s[255];        // total = E
}

__global__ __launch_bounds__(256) void scanC_kernel(
    const u32* __restrict__ counts, const u32* __restrict__ chunkBase,
    u32* __restrict__ offsets, u32* __restrict__ cursor, int N)
{
    __shared__ u32 s[256];
    int t = threadIdx.x, i = blockIdx.x * 256 + t;
    u32 v = (i < N) ? counts[i] : 0u;
    s[t] = v;
    __syncthreads();
    for (int off = 1; off < 256; off <<= 1) {
        u32 a = (t >= off) ? s[t - off] : 0u;
        __syncthreads();
        s[t] += a;
        __syncthreads();
    }
    if (i < N) {
        u32 excl = s[t] - v + chunkBase[blockIdx.x];
        offsets[i] = excl;
        cursor[i]  = excl;
    }
}

// ---------------------------------------------------------------------------
// Kernel 5: fill CSR records packed as (col:u16 | dist_f16:u16).
// ---------------------------------------------------------------------------
__global__ __launch_bounds__(256) void fill_kernel(
    const float* __restrict__ coord, const void* __restrict__ eidx,
    const int* __restrict__ flag, u32* __restrict__ cursor,
    u32* __restrict__ packed, int E)
{
    const bool is64 = (*flag != 0);
    const long long* e64 = (const long long*)eidx;
    const int*       e32 = (const int*)eidx;
    for (int e = blockIdx.x * blockDim.x + threadIdx.x; e < E;
         e += gridDim.x * blockDim.x) {
        int row, col;
        if (is64) { row = (int)e64[e]; col = (int)e64[E + e]; }
        else      { row = e32[e];      col = e32[E + e];      }
        float dx = coord[3 * row + 0] - coord[3 * col + 0];
        float dy = coord[3 * row + 1] - coord[3 * col + 1];
        float dz = coord[3 * row + 2] - coord[3 * col + 2];
        float dist = sqrtf(fmaf(dx, dx, fmaf(dy, dy, dz * dz)));
        u32 pos = atomicAdd(&cursor[row], 1u);
        u16 dh = __half_as_ushort(__float2half(dist));
        packed[pos] = (u32)(unsigned)col | ((u32)dh << 16);
    }
}

// ---------------------------------------------------------------------------
// Kernel 6: pull aggregation. One wave per row; lane owns channels 2l,2l+1.
// H[row] = sum_e relu(y_bf16[col_e] + dist_e * w_vec + c_vec). No atomics.
// ---------------------------------------------------------------------------
__global__ __launch_bounds__(256) void aggregate_kernel(
    const u16* __restrict__ ybf, const u32* __restrict__ offsets,
    const u32* __restrict__ packed, const float* __restrict__ wc,
    float* __restrict__ H, int N)
{
    const int lane = threadIdx.x & 63;
    const int row  = blockIdx.x * 4 + (threadIdx.x >> 6);
    if (row >= N) return;

    const float2 wv = ((const float2*)wc)[lane];
    const float2 cv = ((const float2*)(wc + D))[lane];

    u32 beg = offsets[row], end = offsets[row + 1];
    float a0 = 0.f, a1 = 0.f;
    for (u32 e = beg; e < end; ++e) {
        u32 p = packed[e];                           // wave-uniform
        u32 col = p & 0xFFFFu;
        float dist = __half2float(__ushort_as_half((u16)(p >> 16)));
        u32 yv = *(const u32*)(ybf + (size_t)col * D + 2 * lane);
        float y0 = __uint_as_float(yv << 16);        // bf16 -> f32
        float y1 = __uint_as_float(yv & 0xFFFF0000u);
        a0 += fmaxf(0.f, fmaf(dist, wv.x, y0 + cv.x));
        a1 += fmaxf(0.f, fmaf(dist, wv.y, y1 + cv.y));
    }
    ((float2*)(H + (size_t)row * D))[lane] = make_float2(a0, a1);
}

// ---------------------------------------------------------------------------
// Kernel 7: node GEMM with register-resident W (split-k, 2 threads/channel,
// combine via 512B LDS). No 64KB LDS tile -> no occupancy cap.
// BF16OUT=true:  out = bf16(A @ W)
// BF16OUT=false: out = f32(A @ W + addx + deg*bvec)
// ---------------------------------------------------------------------------
template <bool BF16OUT>
__global__ __launch_bounds__(256) void node_gemm_kernel(
    const float* __restrict__ A, const float* __restrict__ W,
    const float* __restrict__ addx, const u32* __restrict__ degi,
    const float* __restrict__ bvec, void* __restrict__ out, int N)
{
    __shared__ float sm[D];
    const int d  = threadIdx.x & (D - 1);
    const int kh = threadIdx.x >> 7;                 // 0 or 1 (k half)

    float wreg[64];
    #pragma unroll
    for (int j = 0; j < 64; ++j)
        wreg[j] = W[(size_t)(kh * 64 + j) * D + d];  // coalesced per j

    float bv = 0.f;
    if (!BF16OUT) bv = bvec[d];

    for (int n = blockIdx.x; n < N; n += gridDim.x) {
        const float4* a4 = (const float4*)(A + (size_t)n * D) + kh * 16;
        float acc = 0.f;
        #pragma unroll
        for (int q = 0; q < 16; ++q) {               // fully unrolled: static idx
            float4 av = a4[q];
            acc = fmaf(av.x, wreg[4 * q + 0], acc);
            acc = fmaf(av.y, wreg[4 * q + 1], acc);
            acc = fmaf(av.z, wreg[4 * q + 2], acc);
            acc = fmaf(av.w, wreg[4 * q + 3], acc);
        }
        if (kh == 1) sm[d] = acc;
        __syncthreads();
        if (kh == 0) {
            float r = acc + sm[d];
            if (BF16OUT) {
                ((__hip_bfloat16*)out)[(size_t)n * D + d] = __float2bfloat16(r);
            } else {
                r += addx[(size_t)n * D + d];
                r = fmaf((float)degi[n], bv, r);
                ((float*)out)[(size_t)n * D + d] = r;
            }
        }
        __syncthreads();                             // before sm reuse
    }
}

// ---------------------------------------------------------------------------
extern "C" void kernel_launch(void* const* d_in, const int* in_sizes, int n_in,
                              void* d_out, int out_size, void* d_ws, size_t ws_size,
                              hipStream_t stream)
{
    const float* x      = (const float*)d_in[0];
    const float* coord  = (const float*)d_in[1];
    const void*  eidx   = d_in[2];
    const float* W_edge = (const float*)d_in[3];
    const float* b_edge = (const float*)d_in[4];
    const float* W1     = (const float*)d_in[5];
    const float* b1     = (const float*)d_in[6];
    const float* W2     = (const float*)d_in[7];
    const float* b2     = (const float*)d_in[8];

    const int N = in_sizes[1] / 3;       // coord [N,3]
    const int E = in_sizes[2] / 2;       // edge_index [2,E]
    const int NCH = (N + 255) / 256;     // scan chunks (requires N <= 65536)

    // ---- d_ws layout (same 25.8 MB footprint as proven round-1):
    //   H [N*D f32] | counts [N u32] | wc [2D f32] | flag [1]
    float* H      = (float*)d_ws;
    u32*   counts = (u32*)(H + (size_t)N * D);
    float* wc     = (float*)(counts + N);
    int*   flag   = (int*)(wc + 2 * D);

    // ---- d_out doubles as scratch: y(bf16) in the low half, CSR temps above.
    //   y_bf16 [N*D u16] | packed [E u32] | offsets [N+1] | cursor [N]
    //   | chunkSum [NCH] | chunkBase [NCH]          (all dead before final GEMM)
    char* ob      = (char*)d_out;
    u16*  ybf     = (u16*)ob;
    u32*  packed  = (u32*)(ob + (size_t)N * D * 2);
    u32*  offsets = packed + E;
    u32*  cursor  = offsets + (N + 1);
    u32*  chunkSum  = cursor + N;
    u32*  chunkBase = chunkSum + NCH;

    hipMemsetAsync(counts, 0, (size_t)N * sizeof(u32), stream);

    prep_wc_kernel<<<1, 128, 0, stream>>>(W_edge, b_edge, W1, b1, wc);
    detect_kernel<<<1, 256, 0, stream>>>((const int*)eidx,
                                         (E < 1024 ? E : 1024), flag);

    const int EB = (E + 255) / 256;
    count_kernel<<<EB, 256, 0, stream>>>(eidx, flag, counts, E);
    scanA_kernel<<<NCH, 256, 0, stream>>>(counts, chunkSum, N);
    scanB_kernel<<<1, 256, 0, stream>>>(chunkSum, chunkBase, offsets, NCH, N);
    scanC_kernel<<<NCH, 256, 0, stream>>>(counts, chunkBase, offsets, cursor, N);
    fill_kernel<<<EB, 256, 0, stream>>>(coord, eidx, flag, cursor, packed, E);

    // y = bf16(x @ W1_top) into d_out low half
    node_gemm_kernel<true><<<2048, 256, 0, stream>>>(
        x, W1, nullptr, nullptr, nullptr, (void*)ybf, N);

    aggregate_kernel<<<(N + 3) / 4, 256, 0, stream>>>(
        ybf, offsets, packed, wc, H, N);

    // out = x + H @ W2 + deg * b2   (overwrites all of d_out)
    node_gemm_kernel<false><<<2048, 256, 0, stream>>>(
        H, W2, x, counts, b2, d_out, N);
}

// Round 3
// 181.784 us; speedup vs baseline: 4.3827x; 2.3374x over previous
//
#include <hip/hip_runtime.h>
#include <hip/hip_fp16.h>
#include <hip/hip_bf16.h>
#include <math.h>

#define D 128
#define LDAP 136   // padded LDS row length (bf16 elems): 272 B -> bank shift 4/row

typedef unsigned int   u32;
typedef unsigned short u16;
using f32x4 = __attribute__((ext_vector_type(4))) float;
using s16x8 = __attribute__((ext_vector_type(8))) short;

__device__ __forceinline__ u16 f2bf(float f) {       // RNE f32->bf16
    u32 u = __float_as_uint(f);
    return (u16)((u + 0x7FFFu + ((u >> 16) & 1u)) >> 16);
}
__device__ __forceinline__ float bf2f(u16 h) {
    return __uint_as_float((u32)h << 16);
}

// ---------------------------------------------------------------------------
// prep_wc: w_vec[d] = sum_k W_edge[k]*W1[D+k][d]; c_vec[d] = ... + b1[d]
// ---------------------------------------------------------------------------
__global__ __launch_bounds__(128) void prep_wc_kernel(
    const float* __restrict__ W_edge, const float* __restrict__ b_edge,
    const float* __restrict__ W1, const float* __restrict__ b1,
    float* __restrict__ wc)
{
    int d = threadIdx.x;
    float w = 0.f, c = 0.f;
    for (int k = 0; k < D; ++k) {
        float w1 = W1[(size_t)(D + k) * D + d];
        w = fmaf(W_edge[k], w1, w);
        c = fmaf(b_edge[k], w1, c);
    }
    wc[d]     = w;
    wc[D + d] = c + b1[d];
}

// ---------------------------------------------------------------------------
// transpose weights to bf16 row-major-in-K:  Wt[d][k] = W[k][d]
// ---------------------------------------------------------------------------
__global__ __launch_bounds__(128) void transpose_kernel(
    const float* __restrict__ W1, const float* __restrict__ W2,
    u16* __restrict__ Wt1, u16* __restrict__ Wt2)
{
    int d = blockIdx.x, k = threadIdx.x;
    Wt1[d * D + k] = f2bf(W1[(size_t)k * D + d]);   // top half of W1 (k<128)
    Wt2[d * D + k] = f2bf(W2[(size_t)k * D + d]);
}

// ---------------------------------------------------------------------------
// int64-vs-int32 edge_index detection (high words all 0 => int64).
// ---------------------------------------------------------------------------
__global__ __launch_bounds__(256) void detect_kernel(
    const int* __restrict__ idx32, int n_check, int* __restrict__ flag)
{
    __shared__ int nz;
    if (threadIdx.x == 0) nz = 0;
    __syncthreads();
    int local = 0;
    for (int i = threadIdx.x; i < n_check; i += blockDim.x)
        if (idx32[2 * i + 1] != 0) local = 1;
    if (local) atomicOr(&nz, 1);
    __syncthreads();
    if (threadIdx.x == 0) *flag = (nz == 0) ? 1 : 0;
}

// ---------------------------------------------------------------------------
// per-row edge counts
// ---------------------------------------------------------------------------
__global__ __launch_bounds__(256) void count_kernel(
    const void* __restrict__ eidx, const int* __restrict__ flag,
    u32* __restrict__ counts, int E)
{
    const bool is64 = (*flag != 0);
    const long long* e64 = (const long long*)eidx;
    const int*       e32 = (const int*)eidx;
    for (int e = blockIdx.x * blockDim.x + threadIdx.x; e < E;
         e += gridDim.x * blockDim.x) {
        int row = is64 ? (int)e64[e] : e32[e];
        atomicAdd(&counts[row], 1u);
    }
}

// ---------------------------------------------------------------------------
// exclusive scan (N <= 65536)
// ---------------------------------------------------------------------------
__global__ __launch_bounds__(256) void scanA_kernel(
    const u32* __restrict__ counts, u32* __restrict__ chunkSum, int N)
{
    __shared__ u32 s[256];
    int t = threadIdx.x, i = blockIdx.x * 256 + t;
    s[t] = (i < N) ? counts[i] : 0u;
    __syncthreads();
    for (int off = 128; off > 0; off >>= 1) {
        if (t < off) s[t] += s[t + off];
        __syncthreads();
    }
    if (t == 0) chunkSum[blockIdx.x] = s[0];
}

__global__ __launch_bounds__(256) void scanB_kernel(
    const u32* __restrict__ chunkSum, u32* __restrict__ chunkBase,
    u32* __restrict__ offsets, int NCH, int N)
{
    __shared__ u32 s[256];
    int t = threadIdx.x;
    u32 v = (t < NCH) ? chunkSum[t] : 0u;
    s[t] = v;
    __syncthreads();
    for (int off = 1; off < 256; off <<= 1) {
        u32 a = (t >= off) ? s[t - off] : 0u;
        __syncthreads();
        s[t] += a;
        __syncthreads();
    }
    if (t < NCH) chunkBase[t] = s[t] - v;
    if (t == 255) offsets[N] = s[255];
}

__global__ __launch_bounds__(256) void scanC_kernel(
    const u32* __restrict__ counts, const u32* __restrict__ chunkBase,
    u32* __restrict__ offsets, u32* __restrict__ cursor, int N)
{
    __shared__ u32 s[256];
    int t = threadIdx.x, i = blockIdx.x * 256 + t;
    u32 v = (i < N) ? counts[i] : 0u;
    s[t] = v;
    __syncthreads();
    for (int off = 1; off < 256; off <<= 1) {
        u32 a = (t >= off) ? s[t - off] : 0u;
        __syncthreads();
        s[t] += a;
        __syncthreads();
    }
    if (i < N) {
        u32 excl = s[t] - v + chunkBase[blockIdx.x];
        offsets[i] = excl;
        cursor[i]  = excl;
    }
}

// ---------------------------------------------------------------------------
// fill CSR records (col:u16 | dist_f16:u16)
// ---------------------------------------------------------------------------
__global__ __launch_bounds__(256) void fill_kernel(
    const float* __restrict__ coord, const void* __restrict__ eidx,
    const int* __restrict__ flag, u32* __restrict__ cursor,
    u32* __restrict__ packed, int E)
{
    const bool is64 = (*flag != 0);
    const long long* e64 = (const long long*)eidx;
    const int*       e32 = (const int*)eidx;
    for (int e = blockIdx.x * blockDim.x + threadIdx.x; e < E;
         e += gridDim.x * blockDim.x) {
        int row, col;
        if (is64) { row = (int)e64[e]; col = (int)e64[E + e]; }
        else      { row = e32[e];      col = e32[E + e];      }
        float dx = coord[3 * row + 0] - coord[3 * col + 0];
        float dy = coord[3 * row + 1] - coord[3 * col + 1];
        float dz = coord[3 * row + 2] - coord[3 * col + 2];
        float dist = sqrtf(fmaf(dx, dx, fmaf(dy, dy, dz * dz)));
        u32 pos = atomicAdd(&cursor[row], 1u);
        u16 dh = __half_as_ushort(__float2half(dist));
        packed[pos] = (u32)(unsigned)col | ((u32)dh << 16);
    }
}

// ---------------------------------------------------------------------------
// pull aggregation -> H in bf16 (packed pairs). One wave/row, no atomics.
// ---------------------------------------------------------------------------
__global__ __launch_bounds__(256) void aggregate_kernel(
    const u16* __restrict__ ybf, const u32* __restrict__ offsets,
    const u32* __restrict__ packed, const float* __restrict__ wc,
    u32* __restrict__ Hb2, int N)      // Hb2: u32 per 2 channels
{
    const int lane = threadIdx.x & 63;
    const int row  = blockIdx.x * 4 + (threadIdx.x >> 6);
    if (row >= N) return;

    const float2 wv = ((const float2*)wc)[lane];
    const float2 cv = ((const float2*)(wc + D))[lane];

    u32 beg = offsets[row], end = offsets[row + 1];
    float a0 = 0.f, a1 = 0.f;
    u32 p = (beg < end) ? packed[beg] : 0u;
    for (u32 e = beg; e < end; ++e) {
        u32 pn = (e + 1 < end) ? packed[e + 1] : 0u;   // prefetch next record
        u32 col = p & 0xFFFFu;
        float dist = __half2float(__ushort_as_half((u16)(p >> 16)));
        u32 yv = *(const u32*)(ybf + (size_t)col * D + 2 * lane);
        float y0 = __uint_as_float(yv << 16);
        float y1 = __uint_as_float(yv & 0xFFFF0000u);
        a0 += fmaxf(0.f, fmaf(dist, wv.x, y0 + cv.x));
        a1 += fmaxf(0.f, fmaf(dist, wv.y, y1 + cv.y));
        p = pn;
    }
    Hb2[(size_t)row * 64 + lane] = (u32)f2bf(a0) | ((u32)f2bf(a1) << 16);
}

// ---------------------------------------------------------------------------
// MFMA GEMM: out[n][d] = A[n][:] @ W[:,d], K=D=128, via 16x16x32 bf16.
// Block: 4 waves, 64 rows. Wt (bf16 [128][K]) and A-tile staged in padded LDS.
// AMODE 0: A = f32, convert to bf16 while staging.  AMODE 1: A already bf16.
// EPI 0: store bf16 (y).  EPI 1: store f32 acc + x + deg*b2 (final out).
// Fragment pattern per m97 (ref-checked): contiguous 16B = 8 bf16 per lane,
// A row = lane&15, k-chunk = 8*(lane>>4); C/D col=lane&15, row=4*(lane>>4)+reg.
// ---------------------------------------------------------------------------
template <int AMODE, int EPI>
__global__ __launch_bounds__(256) void mfma_gemm_kernel(
    const void* __restrict__ Asrc, const u16* __restrict__ Wt,
    const float* __restrict__ xres, const u32* __restrict__ degi,
    const float* __restrict__ bvec, void* __restrict__ out, int N)
{
    __shared__ u16 wl[D * LDAP];     // 34816 B
    __shared__ u16 al[64 * LDAP];    // 17408 B
    const int t    = threadIdx.x;
    const int lane = t & 63;
    const int w    = t >> 6;
    const int n0   = blockIdx.x * 64;

    // ---- stage Wt (128x128 bf16), coalesced 16B per thread
    #pragma unroll
    for (int i = 0; i < 8; ++i) {
        int e = (i * 256 + t) * 8;
        int r = e >> 7, c = e & 127;
        *(uint4*)&wl[r * LDAP + c] = *(const uint4*)&Wt[r * D + c];
    }
    // ---- stage A tile (64 rows)
    if (AMODE == 0) {
        const float* A = (const float*)Asrc;
        #pragma unroll
        for (int i = 0; i < 8; ++i) {
            int idx = i * 256 + t;           // 2048 float4s
            int r = idx >> 5, c4 = idx & 31;
            int gr = n0 + r; if (gr >= N) gr = N - 1;
            float4 v = *(const float4*)&A[(size_t)gr * D + c4 * 4];
            u32 lo = (u32)f2bf(v.x) | ((u32)f2bf(v.y) << 16);
            u32 hi = (u32)f2bf(v.z) | ((u32)f2bf(v.w) << 16);
            *(uint2*)&al[r * LDAP + c4 * 4] = make_uint2(lo, hi);
        }
    } else {
        const u16* A = (const u16*)Asrc;
        #pragma unroll
        for (int i = 0; i < 4; ++i) {
            int idx = i * 256 + t;           // 1024 uint4s
            int r = idx >> 4, c8 = idx & 15;
            int gr = n0 + r; if (gr >= N) gr = N - 1;
            *(uint4*)&al[r * LDAP + c8 * 8] = *(const uint4*)&A[(size_t)gr * D + c8 * 8];
        }
    }
    __syncthreads();

    const int  fr     = lane & 15;
    const int  kg     = lane >> 4;
    const bool wvalid = (n0 + w * 16) < N;   // N % 16 == 0 -> whole wave valid/invalid

    f32x4 acc[8];
    #pragma unroll
    for (int i = 0; i < 8; ++i) acc[i] = (f32x4){0.f, 0.f, 0.f, 0.f};

    #pragma unroll
    for (int kk = 0; kk < 4; ++kk) {
        const int ko = kk * 32 + kg * 8;
        s16x8 a = *(const s16x8*)&al[(w * 16 + fr) * LDAP + ko];
        #pragma unroll
        for (int ct = 0; ct < 8; ++ct) {
            s16x8 b = *(const s16x8*)&wl[(ct * 16 + fr) * LDAP + ko];
            acc[ct] = __builtin_amdgcn_mfma_f32_16x16x32_bf16(a, b, acc[ct], 0, 0, 0);
        }
    }

    if (!wvalid) return;

    if (EPI == 0) {
        u16* O = (u16*)out;
        #pragma unroll
        for (int ct = 0; ct < 8; ++ct) {
            const int c = ct * 16 + fr;
            #pragma unroll
            for (int j = 0; j < 4; ++j) {
                int R = n0 + w * 16 + 4 * kg + j;
                O[(size_t)R * D + c] = f2bf(acc[ct][j]);
            }
        }
    } else {
        float* O = (float*)out;
        float degf[4];
        #pragma unroll
        for (int j = 0; j < 4; ++j)
            degf[j] = (float)degi[n0 + w * 16 + 4 * kg + j];
        #pragma unroll
        for (int ct = 0; ct < 8; ++ct) {
            const int c  = ct * 16 + fr;
            const float bv = bvec[c];
            #pragma unroll
            for (int j = 0; j < 4; ++j) {
                int R = n0 + w * 16 + 4 * kg + j;
                float r = acc[ct][j] + xres[(size_t)R * D + c] + degf[j] * bv;
                O[(size_t)R * D + c] = r;
            }
        }
    }
}

// ---------------------------------------------------------------------------
extern "C" void kernel_launch(void* const* d_in, const int* in_sizes, int n_in,
                              void* d_out, int out_size, void* d_ws, size_t ws_size,
                              hipStream_t stream)
{
    const float* x      = (const float*)d_in[0];
    const float* coord  = (const float*)d_in[1];
    const void*  eidx   = d_in[2];
    const float* W_edge = (const float*)d_in[3];
    const float* b_edge = (const float*)d_in[4];
    const float* W1     = (const float*)d_in[5];
    const float* b1     = (const float*)d_in[6];
    const float* W2     = (const float*)d_in[7];
    const float* b2     = (const float*)d_in[8];

    const int N   = in_sizes[1] / 3;
    const int E   = in_sizes[2] / 2;
    const int NCH = (N + 255) / 256;

    // ---- d_ws layout (bytes, 64-aligned chunks):
    //   Hb [N*D bf16] | counts [N u32] | wc [2D f32] | flag | Wt1 | Wt2
    char* wsb    = (char*)d_ws;
    u16*  Hb     = (u16*)wsb;                               size_t o = (size_t)N * D * 2;
    u32*  counts = (u32*)(wsb + o);                         o += (size_t)N * 4;
    float* wc    = (float*)(wsb + o);                       o += 2 * D * 4;
    int*  flag   = (int*)(wsb + o);                         o += 64;
    u16*  Wt1    = (u16*)(wsb + o);                         o += D * D * 2;
    u16*  Wt2    = (u16*)(wsb + o);

    // ---- d_out scratch: y(bf16) low half, CSR temps above (dead before GEMM2)
    char* ob      = (char*)d_out;
    u16*  ybf     = (u16*)ob;
    u32*  packed  = (u32*)(ob + (size_t)N * D * 2);
    u32*  offsets = packed + E;
    u32*  cursor  = offsets + (N + 1);
    u32*  chunkSum  = cursor + N;
    u32*  chunkBase = chunkSum + NCH;

    hipMemsetAsync(counts, 0, (size_t)N * sizeof(u32), stream);

    prep_wc_kernel<<<1, 128, 0, stream>>>(W_edge, b_edge, W1, b1, wc);
    transpose_kernel<<<D, D, 0, stream>>>(W1, W2, Wt1, Wt2);
    detect_kernel<<<1, 256, 0, stream>>>((const int*)eidx,
                                         (E < 1024 ? E : 1024), flag);

    const int EB = (E + 255) / 256;
    count_kernel<<<EB, 256, 0, stream>>>(eidx, flag, counts, E);
    scanA_kernel<<<NCH, 256, 0, stream>>>(counts, chunkSum, N);
    scanB_kernel<<<1, 256, 0, stream>>>(chunkSum, chunkBase, offsets, NCH, N);
    scanC_kernel<<<NCH, 256, 0, stream>>>(counts, chunkBase, offsets, cursor, N);
    fill_kernel<<<EB, 256, 0, stream>>>(coord, eidx, flag, cursor, packed, E);

    const int GB = (N + 63) / 64;
    // y = bf16(x @ W1_top)
    mfma_gemm_kernel<0, 0><<<GB, 256, 0, stream>>>(
        x, Wt1, nullptr, nullptr, nullptr, (void*)ybf, N);

    aggregate_kernel<<<(N + 3) / 4, 256, 0, stream>>>(
        ybf, offsets, packed, wc, (u32*)Hb, N);

    // out = x + H @ W2 + deg * b2
    mfma_gemm_kernel<1, 1><<<GB, 256, 0, stream>>>(
        Hb, Wt2, x, counts, b2, d_out, N);
}

// Round 4
// 142.456 us; speedup vs baseline: 5.5927x; 1.2761x over previous
//
#include <hip/hip_runtime.h>
#include <hip/hip_fp16.h>
#include <hip/hip_bf16.h>
#include <math.h>

#define D 128
#define LDAP 136   // padded LDS row length (bf16 elems): 272 B -> 2-way-free banks

typedef unsigned int   u32;
typedef unsigned short u16;
using f32x4 = __attribute__((ext_vector_type(4))) float;
using s16x8 = __attribute__((ext_vector_type(8))) short;

__device__ __forceinline__ u16 f2bf(float f) {       // RNE f32->bf16
    u32 u = __float_as_uint(f);
    return (u16)((u + 0x7FFFu + ((u >> 16) & 1u)) >> 16);
}

// ---------------------------------------------------------------------------
// Per-block int64-vs-int32 edge_index detection. Each wave reads the high
// 32-bit words of the first 64 (assumed-int64) elements; if ALL are zero the
// layout is int64 (random int32 indices would make them nonzero with
// probability 1 - (1/N)^64 ~ 1). Same answer in every block -> deterministic.
// ---------------------------------------------------------------------------
__device__ __forceinline__ bool detect_is64(const int* __restrict__ idx32, int E) {
    int lane = threadIdx.x & 63;
    int hi = 0;
    if (lane < E) hi = idx32[2 * lane + 1];
    return __ballot(hi != 0) == 0ull;
}

// ---------------------------------------------------------------------------
// prep: blocks 0..127 transpose W1_top/W2 to bf16 Wt[d][k]; block 128 builds
//   w_vec[d] = sum_k W_edge[k]*W1[D+k][d], c_vec[d] = sum_k b_edge[k]*W1[D+k][d]+b1[d]
// ---------------------------------------------------------------------------
__global__ __launch_bounds__(128) void prep_fused_kernel(
    const float* __restrict__ W_edge, const float* __restrict__ b_edge,
    const float* __restrict__ W1, const float* __restrict__ b1,
    const float* __restrict__ W2, float* __restrict__ wc,
    u16* __restrict__ Wt1, u16* __restrict__ Wt2)
{
    const int b = blockIdx.x, t = threadIdx.x;
    if (b < D) {
        Wt1[b * D + t] = f2bf(W1[(size_t)t * D + b]);
        Wt2[b * D + t] = f2bf(W2[(size_t)t * D + b]);
    } else {
        float w = 0.f, c = 0.f;
        #pragma unroll 8
        for (int k = 0; k < D; ++k) {
            float w1 = W1[(size_t)(D + k) * D + t];
            w = fmaf(W_edge[k], w1, w);
            c = fmaf(b_edge[k], w1, c);
        }
        wc[t]     = w;
        wc[D + t] = c + b1[t];
    }
}

// ---------------------------------------------------------------------------
// per-row edge counts
// ---------------------------------------------------------------------------
__global__ __launch_bounds__(256) void count_kernel(
    const void* __restrict__ eidx, u32* __restrict__ counts, int E)
{
    const bool is64 = detect_is64((const int*)eidx, E);
    const long long* e64 = (const long long*)eidx;
    const int*       e32 = (const int*)eidx;
    for (int e = blockIdx.x * blockDim.x + threadIdx.x; e < E;
         e += gridDim.x * blockDim.x) {
        int row = is64 ? (int)e64[e] : e32[e];
        atomicAdd(&counts[row], 1u);
    }
}

// ---------------------------------------------------------------------------
// exclusive scan (N <= 65536)
// ---------------------------------------------------------------------------
__global__ __launch_bounds__(256) void scanA_kernel(
    const u32* __restrict__ counts, u32* __restrict__ chunkSum, int N)
{
    __shared__ u32 s[256];
    int t = threadIdx.x, i = blockIdx.x * 256 + t;
    s[t] = (i < N) ? counts[i] : 0u;
    __syncthreads();
    for (int off = 128; off > 0; off >>= 1) {
        if (t < off) s[t] += s[t + off];
        __syncthreads();
    }
    if (t == 0) chunkSum[blockIdx.x] = s[0];
}

__global__ __launch_bounds__(256) void scanB_kernel(
    const u32* __restrict__ chunkSum, u32* __restrict__ chunkBase,
    u32* __restrict__ offsets, int NCH, int N)
{
    __shared__ u32 s[256];
    int t = threadIdx.x;
    u32 v = (t < NCH) ? chunkSum[t] : 0u;
    s[t] = v;
    __syncthreads();
    for (int off = 1; off < 256; off <<= 1) {
        u32 a = (t >= off) ? s[t - off] : 0u;
        __syncthreads();
        s[t] += a;
        __syncthreads();
    }
    if (t < NCH) chunkBase[t] = s[t] - v;
    if (t == 255) offsets[N] = s[255];
}

__global__ __launch_bounds__(256) void scanC_kernel(
    const u32* __restrict__ counts, const u32* __restrict__ chunkBase,
    u32* __restrict__ offsets, u32* __restrict__ cursor, int N)
{
    __shared__ u32 s[256];
    int t = threadIdx.x, i = blockIdx.x * 256 + t;
    u32 v = (i < N) ? counts[i] : 0u;
    s[t] = v;
    __syncthreads();
    for (int off = 1; off < 256; off <<= 1) {
        u32 a = (t >= off) ? s[t - off] : 0u;
        __syncthreads();
        s[t] += a;
        __syncthreads();
    }
    if (i < N) {
        u32 excl = s[t] - v + chunkBase[blockIdx.x];
        offsets[i] = excl;
        cursor[i]  = excl;
    }
}

// ---------------------------------------------------------------------------
// fill CSR records (col:u16 | dist_f16:u16)
// ---------------------------------------------------------------------------
__global__ __launch_bounds__(256) void fill_kernel(
    const float* __restrict__ coord, const void* __restrict__ eidx,
    u32* __restrict__ cursor, u32* __restrict__ packed, int E)
{
    const bool is64 = detect_is64((const int*)eidx, E);
    const long long* e64 = (const long long*)eidx;
    const int*       e32 = (const int*)eidx;
    for (int e = blockIdx.x * blockDim.x + threadIdx.x; e < E;
         e += gridDim.x * blockDim.x) {
        int row, col;
        if (is64) { row = (int)e64[e]; col = (int)e64[E + e]; }
        else      { row = e32[e];      col = e32[E + e];      }
        float dx = coord[3 * row + 0] - coord[3 * col + 0];
        float dy = coord[3 * row + 1] - coord[3 * col + 1];
        float dz = coord[3 * row + 2] - coord[3 * col + 2];
        float dist = sqrtf(fmaf(dx, dx, fmaf(dy, dy, dz * dz)));
        u32 pos = atomicAdd(&cursor[row], 1u);
        u16 dh = __half_as_ushort(__float2half(dist));
        packed[pos] = (u32)(unsigned)col | ((u32)dh << 16);
    }
}

// ---------------------------------------------------------------------------
// pull aggregation -> H bf16. One wave/row, lane owns channels 2l,2l+1.
// 4-deep unroll: 4 independent y-gathers in flight per wave (latency MLP).
// ---------------------------------------------------------------------------
__global__ __launch_bounds__(256) void aggregate_kernel(
    const u16* __restrict__ ybf, const u32* __restrict__ offsets,
    const u32* __restrict__ packed, const float* __restrict__ wc,
    u32* __restrict__ Hb2, int N)
{
    const int lane = threadIdx.x & 63;
    const int row  = blockIdx.x * 4 + (threadIdx.x >> 6);
    if (row >= N) return;

    const float2 wv = ((const float2*)wc)[lane];
    const float2 cv = ((const float2*)(wc + D))[lane];

    const u32 beg = offsets[row], end = offsets[row + 1];
    float a0 = 0.f, a1 = 0.f, b0 = 0.f, b1 = 0.f;
    float c0 = 0.f, c1 = 0.f, d0 = 0.f, d1 = 0.f;

    u32 e = beg;
    for (; e + 4 <= end; e += 4) {
        u32 p0 = packed[e + 0], p1 = packed[e + 1];
        u32 p2 = packed[e + 2], p3 = packed[e + 3];
        u32 y0 = *(const u32*)(ybf + (size_t)(p0 & 0xFFFFu) * D + 2 * lane);
        u32 y1 = *(const u32*)(ybf + (size_t)(p1 & 0xFFFFu) * D + 2 * lane);
        u32 y2 = *(const u32*)(ybf + (size_t)(p2 & 0xFFFFu) * D + 2 * lane);
        u32 y3 = *(const u32*)(ybf + (size_t)(p3 & 0xFFFFu) * D + 2 * lane);
        float t0 = __half2float(__ushort_as_half((u16)(p0 >> 16)));
        float t1 = __half2float(__ushort_as_half((u16)(p1 >> 16)));
        float t2 = __half2float(__ushort_as_half((u16)(p2 >> 16)));
        float t3 = __half2float(__ushort_as_half((u16)(p3 >> 16)));
        a0 += fmaxf(0.f, fmaf(t0, wv.x, __uint_as_float(y0 << 16)        + cv.x));
        a1 += fmaxf(0.f, fmaf(t0, wv.y, __uint_as_float(y0 & 0xFFFF0000u) + cv.y));
        b0 += fmaxf(0.f, fmaf(t1, wv.x, __uint_as_float(y1 << 16)        + cv.x));
        b1 += fmaxf(0.f, fmaf(t1, wv.y, __uint_as_float(y1 & 0xFFFF0000u) + cv.y));
        c0 += fmaxf(0.f, fmaf(t2, wv.x, __uint_as_float(y2 << 16)        + cv.x));
        c1 += fmaxf(0.f, fmaf(t2, wv.y, __uint_as_float(y2 & 0xFFFF0000u) + cv.y));
        d0 += fmaxf(0.f, fmaf(t3, wv.x, __uint_as_float(y3 << 16)        + cv.x));
        d1 += fmaxf(0.f, fmaf(t3, wv.y, __uint_as_float(y3 & 0xFFFF0000u) + cv.y));
    }
    for (; e < end; ++e) {
        u32 p = packed[e];
        float t = __half2float(__ushort_as_half((u16)(p >> 16)));
        u32 yv = *(const u32*)(ybf + (size_t)(p & 0xFFFFu) * D + 2 * lane);
        a0 += fmaxf(0.f, fmaf(t, wv.x, __uint_as_float(yv << 16)        + cv.x));
        a1 += fmaxf(0.f, fmaf(t, wv.y, __uint_as_float(yv & 0xFFFF0000u) + cv.y));
    }
    float r0 = (a0 + b0) + (c0 + d0);
    float r1 = (a1 + b1) + (c1 + d1);
    Hb2[(size_t)row * 64 + lane] = (u32)f2bf(r0) | ((u32)f2bf(r1) << 16);
}

// ---------------------------------------------------------------------------
// MFMA GEMM: out[n][d] = A[n][:] @ W[:,d], K=D=128, via 16x16x32 bf16.
// Block: 4 waves, 64 rows. Wt (bf16 [128][K]) and A-tile staged in padded LDS.
// AMODE 0: A f32 (convert while staging).  AMODE 1: A already bf16.
// EPI 0: store bf16 (y).  EPI 1: store f32 acc + x + deg*b2 (final out).
// ---------------------------------------------------------------------------
template <int AMODE, int EPI>
__global__ __launch_bounds__(256) void mfma_gemm_kernel(
    const void* __restrict__ Asrc, const u16* __restrict__ Wt,
    const float* __restrict__ xres, const u32* __restrict__ degi,
    const float* __restrict__ bvec, void* __restrict__ out, int N)
{
    __shared__ u16 wl[D * LDAP];
    __shared__ u16 al[64 * LDAP];
    const int t    = threadIdx.x;
    const int lane = t & 63;
    const int w    = t >> 6;
    const int n0   = blockIdx.x * 64;

    #pragma unroll
    for (int i = 0; i < 8; ++i) {
        int e = (i * 256 + t) * 8;
        int r = e >> 7, c = e & 127;
        *(uint4*)&wl[r * LDAP + c] = *(const uint4*)&Wt[r * D + c];
    }
    if (AMODE == 0) {
        const float* A = (const float*)Asrc;
        #pragma unroll
        for (int i = 0; i < 8; ++i) {
            int idx = i * 256 + t;
            int r = idx >> 5, c4 = idx & 31;
            int gr = n0 + r; if (gr >= N) gr = N - 1;
            float4 v = *(const float4*)&A[(size_t)gr * D + c4 * 4];
            u32 lo = (u32)f2bf(v.x) | ((u32)f2bf(v.y) << 16);
            u32 hi = (u32)f2bf(v.z) | ((u32)f2bf(v.w) << 16);
            *(uint2*)&al[r * LDAP + c4 * 4] = make_uint2(lo, hi);
        }
    } else {
        const u16* A = (const u16*)Asrc;
        #pragma unroll
        for (int i = 0; i < 4; ++i) {
            int idx = i * 256 + t;
            int r = idx >> 4, c8 = idx & 15;
            int gr = n0 + r; if (gr >= N) gr = N - 1;
            *(uint4*)&al[r * LDAP + c8 * 8] = *(const uint4*)&A[(size_t)gr * D + c8 * 8];
        }
    }
    __syncthreads();

    const int  fr     = lane & 15;
    const int  kg     = lane >> 4;
    const bool wvalid = (n0 + w * 16) < N;

    f32x4 acc[8];
    #pragma unroll
    for (int i = 0; i < 8; ++i) acc[i] = (f32x4){0.f, 0.f, 0.f, 0.f};

    #pragma unroll
    for (int kk = 0; kk < 4; ++kk) {
        const int ko = kk * 32 + kg * 8;
        s16x8 a = *(const s16x8*)&al[(w * 16 + fr) * LDAP + ko];
        #pragma unroll
        for (int ct = 0; ct < 8; ++ct) {
            s16x8 b = *(const s16x8*)&wl[(ct * 16 + fr) * LDAP + ko];
            acc[ct] = __builtin_amdgcn_mfma_f32_16x16x32_bf16(a, b, acc[ct], 0, 0, 0);
        }
    }

    if (!wvalid) return;

    if (EPI == 0) {
        u16* O = (u16*)out;
        #pragma unroll
        for (int ct = 0; ct < 8; ++ct) {
            const int c = ct * 16 + fr;
            #pragma unroll
            for (int j = 0; j < 4; ++j) {
                int R = n0 + w * 16 + 4 * kg + j;
                O[(size_t)R * D + c] = f2bf(acc[ct][j]);
            }
        }
    } else {
        float* O = (float*)out;
        float degf[4];
        #pragma unroll
        for (int j = 0; j < 4; ++j)
            degf[j] = (float)degi[n0 + w * 16 + 4 * kg + j];
        #pragma unroll
        for (int ct = 0; ct < 8; ++ct) {
            const int c  = ct * 16 + fr;
            const float bv = bvec[c];
            #pragma unroll
            for (int j = 0; j < 4; ++j) {
                int R = n0 + w * 16 + 4 * kg + j;
                float r = acc[ct][j] + xres[(size_t)R * D + c] + degf[j] * bv;
                O[(size_t)R * D + c] = r;
            }
        }
    }
}

// ---------------------------------------------------------------------------
extern "C" void kernel_launch(void* const* d_in, const int* in_sizes, int n_in,
                              void* d_out, int out_size, void* d_ws, size_t ws_size,
                              hipStream_t stream)
{
    const float* x      = (const float*)d_in[0];
    const float* coord  = (const float*)d_in[1];
    const void*  eidx   = d_in[2];
    const float* W_edge = (const float*)d_in[3];
    const float* b_edge = (const float*)d_in[4];
    const float* W1     = (const float*)d_in[5];
    const float* b1     = (const float*)d_in[6];
    const float* W2     = (const float*)d_in[7];
    const float* b2     = (const float*)d_in[8];

    const int N   = in_sizes[1] / 3;
    const int E   = in_sizes[2] / 2;
    const int NCH = (N + 255) / 256;

    // ---- d_ws: Hb [N*D bf16] | counts [N u32] | wc [2D f32] | Wt1 | Wt2
    char* wsb    = (char*)d_ws;
    u16*  Hb     = (u16*)wsb;                               size_t o = (size_t)N * D * 2;
    u32*  counts = (u32*)(wsb + o);                         o += (size_t)N * 4;
    float* wc    = (float*)(wsb + o);                       o += 2 * D * 4 + 64;
    u16*  Wt1    = (u16*)(wsb + o);                         o += D * D * 2;
    u16*  Wt2    = (u16*)(wsb + o);

    // ---- d_out scratch: y(bf16) low half, CSR temps above (dead before GEMM2)
    char* ob      = (char*)d_out;
    u16*  ybf     = (u16*)ob;
    u32*  packed  = (u32*)(ob + (size_t)N * D * 2);
    u32*  offsets = packed + E;
    u32*  cursor  = offsets + (N + 1);
    u32*  chunkSum  = cursor + N;
    u32*  chunkBase = chunkSum + NCH;

    hipMemsetAsync(counts, 0, (size_t)N * sizeof(u32), stream);

    prep_fused_kernel<<<D + 1, 128, 0, stream>>>(W_edge, b_edge, W1, b1, W2,
                                                 wc, Wt1, Wt2);

    const int EB = (E + 255) / 256;
    count_kernel<<<EB, 256, 0, stream>>>(eidx, counts, E);
    scanA_kernel<<<NCH, 256, 0, stream>>>(counts, chunkSum, N);
    scanB_kernel<<<1, 256, 0, stream>>>(chunkSum, chunkBase, offsets, NCH, N);
    scanC_kernel<<<NCH, 256, 0, stream>>>(counts, chunkBase, offsets, cursor, N);
    fill_kernel<<<EB, 256, 0, stream>>>(coord, eidx, cursor, packed, E);

    const int GB = (N + 63) / 64;
    mfma_gemm_kernel<0, 0><<<GB, 256, 0, stream>>>(
        x, Wt1, nullptr, nullptr, nullptr, (void*)ybf, N);

    aggregate_kernel<<<(N + 3) / 4, 256, 0, stream>>>(
        ybf, offsets, packed, wc, (u32*)Hb, N);

    mfma_gemm_kernel<1, 1><<<GB, 256, 0, stream>>>(
        Hb, Wt2, x, counts, b2, d_out, N);
}

// Round 6
// 127.313 us; speedup vs baseline: 6.2579x; 1.1189x over previous
//
#include <hip/hip_runtime.h>
#include <hip/hip_fp16.h>
#include <hip/hip_bf16.h>
#include <math.h>

#define D 128
#define LDAP 136   // padded LDS row length (bf16 elems)

typedef unsigned int   u32;
typedef unsigned short u16;
using f32x4 = __attribute__((ext_vector_type(4))) float;
using s16x8 = __attribute__((ext_vector_type(8))) short;
using u32x4 = __attribute__((ext_vector_type(4))) unsigned int;

__device__ __forceinline__ u16 f2bf(float f) {       // RNE f32->bf16
    u32 u = __float_as_uint(f);
    return (u16)((u + 0x7FFFu + ((u >> 16) & 1u)) >> 16);
}

// ---------------------------------------------------------------------------
// Per-wave int64-vs-int32 edge_index detection (high words of first 64
// elements all zero => int64). Deterministic, same answer in every block.
// ---------------------------------------------------------------------------
__device__ __forceinline__ bool detect_is64(const int* __restrict__ idx32, int E) {
    int lane = threadIdx.x & 63;
    int hi = 0;
    if (lane < E) hi = idx32[2 * lane + 1];
    return __ballot(hi != 0) == 0ull;
}

// ---------------------------------------------------------------------------
// prep: blocks 0..127 transpose W1_top/W2 to bf16; block 128 builds w_vec/c_vec.
// ---------------------------------------------------------------------------
__global__ __launch_bounds__(128) void prep_fused_kernel(
    const float* __restrict__ W_edge, const float* __restrict__ b_edge,
    const float* __restrict__ W1, const float* __restrict__ b1,
    const float* __restrict__ W2, float* __restrict__ wc,
    u16* __restrict__ Wt1, u16* __restrict__ Wt2)
{
    const int b = blockIdx.x, t = threadIdx.x;
    if (b < D) {
        Wt1[b * D + t] = f2bf(W1[(size_t)t * D + b]);
        Wt2[b * D + t] = f2bf(W2[(size_t)t * D + b]);
    } else {
        float w = 0.f, c = 0.f;
        #pragma unroll 8
        for (int k = 0; k < D; ++k) {
            float w1 = W1[(size_t)(D + k) * D + t];
            w = fmaf(W_edge[k], w1, w);
            c = fmaf(b_edge[k], w1, c);
        }
        wc[t]     = w;
        wc[D + t] = c + b1[t];
    }
}

// ---------------------------------------------------------------------------
// wide-grid zero (replaces 40us rocclr fillBuffer)
// ---------------------------------------------------------------------------
__global__ __launch_bounds__(256) void zero_kernel(u32x4* __restrict__ p, int n4)
{
    int i = blockIdx.x * 256 + threadIdx.x;
    if (i < n4) p[i] = (u32x4){0u, 0u, 0u, 0u};
}

// ---------------------------------------------------------------------------
// count: 4 edges/thread. atomicAdd returns the within-row sequence number;
// store rowseq = row<<16|seq and colDist = col|f16(dist)<<16 coalesced (nt).
// ---------------------------------------------------------------------------
__global__ __launch_bounds__(256) void count_kernel(
    const void* __restrict__ eidx, const float* __restrict__ coord,
    u32* __restrict__ counts, u32* __restrict__ rowseq,
    u32* __restrict__ colDist, int E)
{
    const bool is64 = detect_is64((const int*)eidx, E);
    const long long* e64 = (const long long*)eidx;
    const int*       e32 = (const int*)eidx;
    const int tid    = blockIdx.x * blockDim.x + threadIdx.x;
    const int stride = gridDim.x * blockDim.x;
    const int e4     = E & ~3;

    for (int e0 = tid * 4; e0 < e4; e0 += stride * 4) {
        int rows[4], cols[4];
        if (is64) {
            #pragma unroll
            for (int j = 0; j < 4; ++j) {
                rows[j] = (int)e64[e0 + j];
                cols[j] = (int)e64[E + e0 + j];
            }
        } else {
            #pragma unroll
            for (int j = 0; j < 4; ++j) {
                rows[j] = e32[e0 + j];
                cols[j] = e32[E + e0 + j];
            }
        }
        float dist[4];
        #pragma unroll
        for (int j = 0; j < 4; ++j) {
            float dx = coord[3 * rows[j] + 0] - coord[3 * cols[j] + 0];
            float dy = coord[3 * rows[j] + 1] - coord[3 * cols[j] + 1];
            float dz = coord[3 * rows[j] + 2] - coord[3 * cols[j] + 2];
            dist[j] = sqrtf(fmaf(dx, dx, fmaf(dy, dy, dz * dz)));
        }
        u32x4 rs, cd;
        #pragma unroll
        for (int j = 0; j < 4; ++j) {
            u32 seq = atomicAdd(&counts[rows[j]], 1u);
            rs[j] = ((u32)rows[j] << 16) | (seq & 0xFFFFu);
            cd[j] = (u32)cols[j] |
                    ((u32)__half_as_ushort(__float2half(dist[j])) << 16);
        }
        __builtin_nontemporal_store(rs, (u32x4*)&rowseq[e0]);
        __builtin_nontemporal_store(cd, (u32x4*)&colDist[e0]);
    }
    if (tid < E - e4) {        // scalar tail (E % 4 edges)
        int e = e4 + tid;
        int row = is64 ? (int)e64[e] : e32[e];
        int col = is64 ? (int)e64[E + e] : e32[E + e];
        float dx = coord[3 * row + 0] - coord[3 * col + 0];
        float dy = coord[3 * row + 1] - coord[3 * col + 1];
        float dz = coord[3 * row + 2] - coord[3 * col + 2];
        float dist = sqrtf(fmaf(dx, dx, fmaf(dy, dy, dz * dz)));
        u32 seq = atomicAdd(&counts[row], 1u);
        rowseq[e]  = ((u32)row << 16) | (seq & 0xFFFFu);
        colDist[e] = (u32)col | ((u32)__half_as_ushort(__float2half(dist)) << 16);
    }
}

// ---------------------------------------------------------------------------
// exclusive scan (N <= 65536)
// ---------------------------------------------------------------------------
__global__ __launch_bounds__(256) void scanA_kernel(
    const u32* __restrict__ counts, u32* __restrict__ chunkSum, int N)
{
    __shared__ u32 s[256];
    int t = threadIdx.x, i = blockIdx.x * 256 + t;
    s[t] = (i < N) ? counts[i] : 0u;
    __syncthreads();
    for (int off = 128; off > 0; off >>= 1) {
        if (t < off) s[t] += s[t + off];
        __syncthreads();
    }
    if (t == 0) chunkSum[blockIdx.x] = s[0];
}

__global__ __launch_bounds__(256) void scanB_kernel(
    const u32* __restrict__ chunkSum, u32* __restrict__ chunkBase,
    u32* __restrict__ offsets, int NCH, int N)
{
    __shared__ u32 s[256];
    int t = threadIdx.x;
    u32 v = (t < NCH) ? chunkSum[t] : 0u;
    s[t] = v;
    __syncthreads();
    for (int off = 1; off < 256; off <<= 1) {
        u32 a = (t >= off) ? s[t - off] : 0u;
        __syncthreads();
        s[t] += a;
        __syncthreads();
    }
    if (t < NCH) chunkBase[t] = s[t] - v;
    if (t == 255) offsets[N] = s[255];
}

__global__ __launch_bounds__(256) void scanC_kernel(
    const u32* __restrict__ counts, const u32* __restrict__ chunkBase,
    u32* __restrict__ offsets, int N)
{
    __shared__ u32 s[256];
    int t = threadIdx.x, i = blockIdx.x * 256 + t;
    u32 v = (i < N) ? counts[i] : 0u;
    s[t] = v;
    __syncthreads();
    for (int off = 1; off < 256; off <<= 1) {
        u32 a = (t >= off) ? s[t - off] : 0u;
        __syncthreads();
        s[t] += a;
        __syncthreads();
    }
    if (i < N) offsets[i] = s[t] - v + chunkBase[blockIdx.x];
}

// ---------------------------------------------------------------------------
// scatter: pos = offsets[row] + seq; packed[pos] = colDist. No atomics.
// ---------------------------------------------------------------------------
__global__ __launch_bounds__(256) void scatter_kernel(
    const u32* __restrict__ rowseq, const u32* __restrict__ colDist,
    const u32* __restrict__ offsets, u32* __restrict__ packed, int E)
{
    const int tid = blockIdx.x * blockDim.x + threadIdx.x;
    const int e4  = E & ~3;
    const int e0  = tid * 4;
    if (e0 < e4) {
        u32x4 rs = *(const u32x4*)&rowseq[e0];
        u32x4 cd = *(const u32x4*)&colDist[e0];
        u32 p0 = offsets[rs.x >> 16] + (rs.x & 0xFFFFu);
        u32 p1 = offsets[rs.y >> 16] + (rs.y & 0xFFFFu);
        u32 p2 = offsets[rs.z >> 16] + (rs.z & 0xFFFFu);
        u32 p3 = offsets[rs.w >> 16] + (rs.w & 0xFFFFu);
        __builtin_nontemporal_store(cd.x, &packed[p0]);
        __builtin_nontemporal_store(cd.y, &packed[p1]);
        __builtin_nontemporal_store(cd.z, &packed[p2]);
        __builtin_nontemporal_store(cd.w, &packed[p3]);
    }
    if (tid < E - e4) {
        int e = e4 + tid;
        u32 rs = rowseq[e];
        packed[offsets[rs >> 16] + (rs & 0xFFFFu)] = colDist[e];
    }
}

// ---------------------------------------------------------------------------
// pull aggregation -> H bf16. One wave/row, lane owns channels 2l,2l+1.
// 8-deep unroll: 8 independent y-gathers in flight per wave.
// ---------------------------------------------------------------------------
__global__ __launch_bounds__(256) void aggregate_kernel(
    const u16* __restrict__ ybf, const u32* __restrict__ offsets,
    const u32* __restrict__ packed, const float* __restrict__ wc,
    u32* __restrict__ Hb2, int N)
{
    const int lane = threadIdx.x & 63;
    const int row  = blockIdx.x * 4 + (threadIdx.x >> 6);
    if (row >= N) return;

    const float2 wv = ((const float2*)wc)[lane];
    const float2 cv = ((const float2*)(wc + D))[lane];

    const u32 beg = offsets[row], end = offsets[row + 1];
    float a0[4] = {0.f, 0.f, 0.f, 0.f};
    float a1[4] = {0.f, 0.f, 0.f, 0.f};

    u32 e = beg;
    for (; e + 8 <= end; e += 8) {
        u32 p[8], yv[8];
        #pragma unroll
        for (int j = 0; j < 8; ++j) p[j] = packed[e + j];
        #pragma unroll
        for (int j = 0; j < 8; ++j)
            yv[j] = *(const u32*)(ybf + (size_t)(p[j] & 0xFFFFu) * D + 2 * lane);
        #pragma unroll
        for (int j = 0; j < 8; ++j) {
            float t = __half2float(__ushort_as_half((u16)(p[j] >> 16)));
            a0[j & 3] += fmaxf(0.f, fmaf(t, wv.x, __uint_as_float(yv[j] << 16)         + cv.x));
            a1[j & 3] += fmaxf(0.f, fmaf(t, wv.y, __uint_as_float(yv[j] & 0xFFFF0000u) + cv.y));
        }
    }
    for (; e + 4 <= end; e += 4) {
        u32 p[4], yv[4];
        #pragma unroll
        for (int j = 0; j < 4; ++j) p[j] = packed[e + j];
        #pragma unroll
        for (int j = 0; j < 4; ++j)
            yv[j] = *(const u32*)(ybf + (size_t)(p[j] & 0xFFFFu) * D + 2 * lane);
        #pragma unroll
        for (int j = 0; j < 4; ++j) {
            float t = __half2float(__ushort_as_half((u16)(p[j] >> 16)));
            a0[j] += fmaxf(0.f, fmaf(t, wv.x, __uint_as_float(yv[j] << 16)         + cv.x));
            a1[j] += fmaxf(0.f, fmaf(t, wv.y, __uint_as_float(yv[j] & 0xFFFF0000u) + cv.y));
        }
    }
    for (; e < end; ++e) {
        u32 p = packed[e];
        float t = __half2float(__ushort_as_half((u16)(p >> 16)));
        u32 yv = *(const u32*)(ybf + (size_t)(p & 0xFFFFu) * D + 2 * lane);
        a0[0] += fmaxf(0.f, fmaf(t, wv.x, __uint_as_float(yv << 16)         + cv.x));
        a1[0] += fmaxf(0.f, fmaf(t, wv.y, __uint_as_float(yv & 0xFFFF0000u) + cv.y));
    }
    float r0 = (a0[0] + a0[1]) + (a0[2] + a0[3]);
    float r1 = (a1[0] + a1[1]) + (a1[2] + a1[3]);
    Hb2[(size_t)row * 64 + lane] = (u32)f2bf(r0) | ((u32)f2bf(r1) << 16);
}

// ---------------------------------------------------------------------------
// MFMA GEMM: out[n][d] = A[n][:] @ W[:,d], K=D=128, via 16x16x32 bf16.
// AMODE 0: A f32 (convert while staging). AMODE 1: A already bf16.
// EPI 0: store bf16 (y). EPI 1: store f32 acc + x + deg*b2 (final out).
// ---------------------------------------------------------------------------
template <int AMODE, int EPI>
__global__ __launch_bounds__(256) void mfma_gemm_kernel(
    const void* __restrict__ Asrc, const u16* __restrict__ Wt,
    const float* __restrict__ xres, const u32* __restrict__ degi,
    const float* __restrict__ bvec, void* __restrict__ out, int N)
{
    __shared__ u16 wl[D * LDAP];
    __shared__ u16 al[64 * LDAP];
    const int t    = threadIdx.x;
    const int lane = t & 63;
    const int w    = t >> 6;
    const int n0   = blockIdx.x * 64;

    #pragma unroll
    for (int i = 0; i < 8; ++i) {
        int e = (i * 256 + t) * 8;
        int r = e >> 7, c = e & 127;
        *(u32x4*)&wl[r * LDAP + c] = *(const u32x4*)&Wt[r * D + c];
    }
    if (AMODE == 0) {
        const float* A = (const float*)Asrc;
        #pragma unroll
        for (int i = 0; i < 8; ++i) {
            int idx = i * 256 + t;
            int r = idx >> 5, c4 = idx & 31;
            int gr = n0 + r; if (gr >= N) gr = N - 1;
            float4 v = *(const float4*)&A[(size_t)gr * D + c4 * 4];
            u32 lo = (u32)f2bf(v.x) | ((u32)f2bf(v.y) << 16);
            u32 hi = (u32)f2bf(v.z) | ((u32)f2bf(v.w) << 16);
            *(uint2*)&al[r * LDAP + c4 * 4] = make_uint2(lo, hi);
        }
    } else {
        const u16* A = (const u16*)Asrc;
        #pragma unroll
        for (int i = 0; i < 4; ++i) {
            int idx = i * 256 + t;
            int r = idx >> 4, c8 = idx & 15;
            int gr = n0 + r; if (gr >= N) gr = N - 1;
            *(u32x4*)&al[r * LDAP + c8 * 8] = *(const u32x4*)&A[(size_t)gr * D + c8 * 8];
        }
    }
    __syncthreads();

    const int  fr     = lane & 15;
    const int  kg     = lane >> 4;
    const bool wvalid = (n0 + w * 16) < N;

    f32x4 acc[8];
    #pragma unroll
    for (int i = 0; i < 8; ++i) acc[i] = (f32x4){0.f, 0.f, 0.f, 0.f};

    #pragma unroll
    for (int kk = 0; kk < 4; ++kk) {
        const int ko = kk * 32 + kg * 8;
        s16x8 a = *(const s16x8*)&al[(w * 16 + fr) * LDAP + ko];
        #pragma unroll
        for (int ct = 0; ct < 8; ++ct) {
            s16x8 b = *(const s16x8*)&wl[(ct * 16 + fr) * LDAP + ko];
            acc[ct] = __builtin_amdgcn_mfma_f32_16x16x32_bf16(a, b, acc[ct], 0, 0, 0);
        }
    }

    if (!wvalid) return;

    if (EPI == 0) {
        u16* O = (u16*)out;
        #pragma unroll
        for (int ct = 0; ct < 8; ++ct) {
            const int c = ct * 16 + fr;
            #pragma unroll
            for (int j = 0; j < 4; ++j) {
                int R = n0 + w * 16 + 4 * kg + j;
                O[(size_t)R * D + c] = f2bf(acc[ct][j]);
            }
        }
    } else {
        float* O = (float*)out;
        float degf[4];
        #pragma unroll
        for (int j = 0; j < 4; ++j)
            degf[j] = (float)degi[n0 + w * 16 + 4 * kg + j];
        #pragma unroll
        for (int ct = 0; ct < 8; ++ct) {
            const int c  = ct * 16 + fr;
            const float bv = bvec[c];
            #pragma unroll
            for (int j = 0; j < 4; ++j) {
                int R = n0 + w * 16 + 4 * kg + j;
                float r = acc[ct][j] + xres[(size_t)R * D + c] + degf[j] * bv;
                O[(size_t)R * D + c] = r;
            }
        }
    }
}

// ---------------------------------------------------------------------------
extern "C" void kernel_launch(void* const* d_in, const int* in_sizes, int n_in,
                              void* d_out, int out_size, void* d_ws, size_t ws_size,
                              hipStream_t stream)
{
    const float* x      = (const float*)d_in[0];
    const float* coord  = (const float*)d_in[1];
    const void*  eidx   = d_in[2];
    const float* W_edge = (const float*)d_in[3];
    const float* b_edge = (const float*)d_in[4];
    const float* W1     = (const float*)d_in[5];
    const float* b1     = (const float*)d_in[6];
    const float* W2     = (const float*)d_in[7];
    const float* b2     = (const float*)d_in[8];

    const int N   = in_sizes[1] / 3;
    const int E   = in_sizes[2] / 2;
    const int EA  = (E + 3) & ~3;          // 16B-aligned element stride
    const int NCH = (N + 255) / 256;

    // ---- d_ws: Hb [N*D bf16] | counts [(N+16) u32] | wc [2D f32] | Wt1 | Wt2
    char* wsb    = (char*)d_ws;
    u16*  Hb     = (u16*)wsb;                 size_t o = (size_t)N * D * 2;
    u32*  counts = (u32*)(wsb + o);           o += (size_t)(N + 16) * 4;
    float* wc    = (float*)(wsb + o);         o += 2 * D * 4 + 64;
    u16*  Wt1    = (u16*)(wsb + o);           o += D * D * 2;
    u16*  Wt2    = (u16*)(wsb + o);

    // ---- d_out scratch (upper half; all dead before final GEMM writes):
    //   ybf [N*D bf16] | rowseq [EA] | colDist [EA] | packed [EA]
    //   | offsets [N+1] | chunkSum [NCH] | chunkBase [NCH]
    char* ob        = (char*)d_out;
    u16*  ybf       = (u16*)ob;
    u32*  rowseq    = (u32*)(ob + (size_t)N * D * 2);
    u32*  colDist   = rowseq + EA;
    u32*  packed    = colDist + EA;
    u32*  offsets   = packed + EA;
    u32*  chunkSum  = offsets + (N + 1);
    u32*  chunkBase = chunkSum + NCH;

    prep_fused_kernel<<<D + 1, 128, 0, stream>>>(W_edge, b_edge, W1, b1, W2,
                                                 wc, Wt1, Wt2);

    const int NZ4 = (N + 3) / 4;                       // counts padded to 16
    zero_kernel<<<(NZ4 + 255) / 256, 256, 0, stream>>>((u32x4*)counts, NZ4);

    const int CB = (E / 4 + 255) / 256;
    count_kernel<<<CB, 256, 0, stream>>>(eidx, coord, counts,
                                         rowseq, colDist, E);
    scanA_kernel<<<NCH, 256, 0, stream>>>(counts, chunkSum, N);
    scanB_kernel<<<1, 256, 0, stream>>>(chunkSum, chunkBase, offsets, NCH, N);
    scanC_kernel<<<NCH, 256, 0, stream>>>(counts, chunkBase, offsets, N);
    scatter_kernel<<<CB, 256, 0, stream>>>(rowseq, colDist, offsets, packed, E);

    const int GB = (N + 63) / 64;
    mfma_gemm_kernel<0, 0><<<GB, 256, 0, stream>>>(
        x, Wt1, nullptr, nullptr, nullptr, (void*)ybf, N);

    aggregate_kernel<<<(N + 3) / 4, 256, 0, stream>>>(
        ybf, offsets, packed, wc, (u32*)Hb, N);

    mfma_gemm_kernel<1, 1><<<GB, 256, 0, stream>>>(
        Hb, Wt2, x, counts, b2, d_out, N);
}